// Round 10
// baseline (318.372 us; speedup 1.0000x reference)
//
#include <hip/hip_runtime.h>

typedef __attribute__((ext_vector_type(8))) short short8;
typedef __attribute__((ext_vector_type(4))) float f32x4;
typedef __attribute__((ext_vector_type(4))) unsigned short us4;
typedef unsigned short u16;

#define kB 4
#define kC 512
#define kCr 8
#define kH 96
#define kW 96
#define kHW 9216
#define kCHW 4718592
#define NEGV -1e9f

__device__ __forceinline__ u16 f2b(float f) {
  union { float f; unsigned u; } v; v.f = f;
  unsigned r = v.u + 0x7fff + ((v.u >> 16) & 1);
  return (u16)(r >> 16);
}
__device__ __forceinline__ float b2f(u16 h) {
  union { unsigned u; float f; } v; v.u = ((unsigned)h) << 16;
  return v.f;
}
#define MFMA(a, b, c) __builtin_amdgcn_mfma_f32_16x16x32_bf16(a, b, c, 0, 0, 0)

// async global->LDS, 16B per lane. LDS dest must be wave-uniform-base + lane*16.
__device__ __forceinline__ void gl16(const u16* g, u16* l) {
  __builtin_amdgcn_global_load_lds(
      (const __attribute__((address_space(1))) void*)g,
      (__attribute__((address_space(3))) void*)l, 16, 0, 0);
}

// ---------- fp32 [R][C] -> bf16 [C][R] transpose-convert, 64x64 tiles ----------
__global__ __launch_bounds__(256) void k_cvt_T(const float* __restrict__ in,
                                               u16* __restrict__ out,
                                               int R, int C) {
  const float* ib = in + (size_t)blockIdx.z * R * C;
  u16* ob = out + (size_t)blockIdx.z * R * C;
  int c0 = blockIdx.x * 64, r0 = blockIdx.y * 64;
  __shared__ u16 T[64][68];
  int tid = threadIdx.x;
#pragma unroll
  for (int p = 0; p < 4; p++) {
    int ch = tid + p * 256;
    int i = ch >> 4, seg = ch & 15;
    f32x4 v = *(const f32x4*)&ib[(size_t)(r0 + i) * C + c0 + seg * 4];
    T[i][seg*4+0] = f2b(v[0]); T[i][seg*4+1] = f2b(v[1]);
    T[i][seg*4+2] = f2b(v[2]); T[i][seg*4+3] = f2b(v[3]);
  }
  __syncthreads();
#pragma unroll
  for (int p = 0; p < 4; p++) {
    int ch = tid + p * 256;
    int j = ch >> 4, seg = ch & 15;
    us4 o;
#pragma unroll
    for (int e = 0; e < 4; e++) o[e] = T[seg*4+e][j];
    *(us4*)&ob[(size_t)(c0 + j) * R + r0 + seg * 4] = o;
  }
}

// ---------- weights fp32 -> bf16: wco[0:512]=w_c, wco[512:1024]=w_o ----------
__global__ __launch_bounds__(256) void k_cvtw(const float* __restrict__ wc,
                                              const float* __restrict__ wo,
                                              u16* __restrict__ wco) {
  int i = blockIdx.x * 256 + threadIdx.x;   // 131072 chunks of 4 floats
  const float* src = (i < 65536) ? &wc[(size_t)i * 4] : &wo[(size_t)(i - 65536) * 4];
  f32x4 v = *(const f32x4*)src;
  us4 o;
  o[0] = f2b(v[0]); o[1] = f2b(v[1]); o[2] = f2b(v[2]); o[3] = f2b(v[3]);
  ((us4*)wco)[i] = o;
}

// ---------- small convs via MFMA: fhw[b][r][hw], r<8: w_h conv, r>=8: w_w conv ----------
__global__ __launch_bounds__(256) void k_conv16(
    const float* __restrict__ wh, const float* __restrict__ bh,
    const float* __restrict__ ww, const float* __restrict__ bw,
    const u16* __restrict__ XT, u16* __restrict__ Out) {
  __shared__ u16 As[16][520];
  __shared__ float bias_s[16];
  int tid = threadIdx.x;
#pragma unroll
  for (int p = 0; p < 4; p++) {
    int ch = tid + p * 256;               // 1024 chunks of 8 elems
    int r = ch >> 6, seg = ch & 63;
    const float* src = (r < 8) ? &wh[r * 512 + seg * 8] : &ww[(r - 8) * 512 + seg * 8];
    f32x4 v0 = *(const f32x4*)src;
    f32x4 v1 = *(const f32x4*)(src + 4);
    short8 sv;
    sv[0]=f2b(v0[0]); sv[1]=f2b(v0[1]); sv[2]=f2b(v0[2]); sv[3]=f2b(v0[3]);
    sv[4]=f2b(v1[0]); sv[5]=f2b(v1[1]); sv[6]=f2b(v1[2]); sv[7]=f2b(v1[3]);
    *(short8*)&As[r][seg * 8] = sv;
  }
  if (tid < 16) bias_s[tid] = (tid < 8) ? bh[tid] : bw[tid - 8];
  __syncthreads();
  int b = blockIdx.y;
  int nb = blockIdx.x * 128 + (tid >> 6) * 32;   // wave's 32-n strip
  int lane = tid & 63;
  int lr = lane & 15, lg = lane >> 4;
  const u16* Bb = XT + (size_t)b * kCHW;
  f32x4 acc[2] = {};
#pragma unroll 4
  for (int k0 = 0; k0 < 512; k0 += 32) {
    short8 a = *(const short8*)&As[lr][k0 + lg * 8];
    short8 b0 = *(const short8*)&Bb[(size_t)(nb + lr) * 512 + k0 + lg * 8];
    short8 b1 = *(const short8*)&Bb[(size_t)(nb + 16 + lr) * 512 + k0 + lg * 8];
    acc[0] = MFMA(a, b0, acc[0]);
    acc[1] = MFMA(a, b1, acc[1]);
  }
#pragma unroll
  for (int q = 0; q < 2; q++)
#pragma unroll
    for (int r = 0; r < 4; r++) {
      int m = lg * 4 + r;
      Out[((size_t)b * 16 + m) * kHW + nb + q * 16 + lr] = f2b(acc[q][r] + bias_s[m]);
    }
}

// ======== shared pipelined 128x128 GEMM pieces (A.B^T, K-major rows) ========
#define GEMM_PROLOG()                                                      \
  int tid = threadIdx.x;                                                   \
  int lane = tid & 63, wv = tid >> 6;                                      \
  int wr = (wv >> 1) * 64, wc = (wv & 1) * 64;                             \
  int lr = lane & 15, lg = lane >> 4;                                      \
  f32x4 acc[4][4] = {};

#define STAGE(bufv, kk)                                                    \
  {                                                                        \
    _Pragma("unroll")                                                      \
    for (int p = 0; p < 4; p++) {                                          \
      int ch = tid + p * 256;                                              \
      int row = ch >> 3, cc = ch & 7;                                      \
      int sc = (cc ^ (row & 7)) * 8;                                       \
      gl16(&Asrc[(size_t)(bm + row) * LDA + (kk) + sc], &As[bufv][row][cc * 8]); \
      gl16(&Bsrc[(size_t)(bn + row) * LDB + (kk) + sc], &Bs[bufv][row][cc * 8]); \
    }                                                                      \
  }

#define COMPUTE_T(bufv, ACC)                                               \
  {                                                                        \
    _Pragma("unroll")                                                      \
    for (int ks = 0; ks < 2; ks++) {                                       \
      int ca = ((ks * 4 + lg) ^ (lr & 7)) * 8;                             \
      short8 av[4], bv[4];                                                 \
      _Pragma("unroll")                                                    \
      for (int m = 0; m < 4; m++)                                          \
        av[m] = *(const short8*)&As[bufv][wr + m * 16 + lr][ca];           \
      _Pragma("unroll")                                                    \
      for (int n = 0; n < 4; n++)                                          \
        bv[n] = *(const short8*)&Bs[bufv][wc + n * 16 + lr][ca];           \
      __builtin_amdgcn_s_setprio(1);                                       \
      _Pragma("unroll")                                                    \
      for (int m = 0; m < 4; m++)                                          \
        _Pragma("unroll")                                                  \
        for (int n = 0; n < 4; n++)                                        \
          ACC[m][n] = MFMA(av[m], bv[n], ACC[m][n]);                       \
      __builtin_amdgcn_s_setprio(0);                                       \
    }                                                                      \
  }

#define COMPUTE(bufv) COMPUTE_T(bufv, acc)

#define VMBAR(N)                                                           \
  asm volatile("s_waitcnt vmcnt(" #N ")" ::: "memory");                    \
  __builtin_amdgcn_s_barrier();

#define LGBAR                                                              \
  asm volatile("s_waitcnt lgkmcnt(0)" ::: "memory");                       \
  __builtin_amdgcn_s_barrier();

#define PIPELOOP(NT, KBASE)                                                \
  STAGE(0, (KBASE));                                                       \
  STAGE(1, (KBASE) + 64);                                                  \
  {                                                                        \
    int cur = 0;                                                           \
    _Pragma("unroll 1")                                                    \
    for (int t = 0; t < (NT) - 2; t++) {                                   \
      VMBAR(8);                                                            \
      COMPUTE(cur);                                                        \
      LGBAR;                                                               \
      STAGE(cur, (KBASE) + (t + 2) * 64);                                  \
      cur ^= 1;                                                            \
    }                                                                      \
    VMBAR(8);                                                              \
    COMPUTE(cur);                                                          \
    cur ^= 1;                                                              \
    VMBAR(0);                                                              \
    COMPUTE(cur);                                                          \
  }

// ---------- merged conv1x1 GEMM, K-pipeline folded x2 over bn ----------
// One block: bn0 and bn0+128 tiles in ONE continuous 16-tile pipeline.
// w_c half (bm<512) also writes f_chT[hw][o] via LDS-transposed full-line stores.
__global__ __launch_bounds__(256) void k_gemm_conv2(
    const u16* __restrict__ wco, const u16* __restrict__ BT,
    const float* __restrict__ b_c, const float* __restrict__ b_o,
    u16* __restrict__ f_ch, u16* __restrict__ f_cha, u16* __restrict__ f_chT) {
  __shared__ u16 smem[32768];   // 64 KB: [2][128][64] As + [2][128][64] Bs, reused as T
  u16 (*As)[128][64] = (u16 (*)[128][64])smem;
  u16 (*Bs)[128][64] = (u16 (*)[128][64])(smem + 16384);
  int tid = threadIdx.x;
  int lane = tid & 63, wv = tid >> 6;
  int wr = (wv >> 1) * 64, wc = (wv & 1) * 64;
  int lr = lane & 15, lg = lane >> 4;
  int b = blockIdx.z;
  int bm = blockIdx.y * 128;   // o in [0,1024)
  int bn0 = blockIdx.x * 256;  // hw pair base
  const u16* Asrc = wco;
  const u16* Bsrc = BT + (size_t)b * kCHW;
  f32x4 acc0[4][4] = {};
  f32x4 acc1[4][4] = {};

#define F_STG(bufv, g)                                                     \
  {                                                                        \
    int kk_ = ((g) & 7) * 64;                                              \
    int bn_ = bn0 + (((g) >> 3) & 1) * 128;                                \
    _Pragma("unroll")                                                      \
    for (int p = 0; p < 4; p++) {                                          \
      int ch = tid + p * 256;                                              \
      int row = ch >> 3, cc = ch & 7;                                      \
      int sc = (cc ^ (row & 7)) * 8;                                       \
      gl16(&Asrc[(size_t)(bm + row) * 512 + kk_ + sc], &As[bufv][row][cc * 8]); \
      gl16(&Bsrc[(size_t)(bn_ + row) * 512 + kk_ + sc], &Bs[bufv][row][cc * 8]); \
    }                                                                      \
  }

  F_STG(0, 0);
  F_STG(1, 1);
  int cur = 0;
#pragma unroll 1
  for (int t = 0; t < 8; t++) {          // tiles 0..7 -> acc0 (seg 0)
    VMBAR(8);
    COMPUTE_T(cur, acc0);
    LGBAR;
    F_STG(cur, t + 2);                   // stages up to tile 9
    cur ^= 1;
  }
#pragma unroll 1
  for (int t = 8; t < 14; t++) {         // tiles 8..13 -> acc1 (seg 1)
    VMBAR(8);
    COMPUTE_T(cur, acc1);
    LGBAR;
    F_STG(cur, t + 2);                   // stages up to tile 15
    cur ^= 1;
  }
  VMBAR(8);
  COMPUTE_T(cur, acc1);                  // tile 14
  cur ^= 1;
  VMBAR(0);
  COMPUTE_T(cur, acc1);                  // tile 15

  const float* biasp = (bm < 512) ? (b_c + bm) : (b_o + bm - 512);
  u16* Ob = (bm < 512) ? (f_ch + (size_t)b * kCHW + (size_t)bm * kHW)
                       : (f_cha + (size_t)b * kCHW + (size_t)(bm - 512) * kHW);
  float biasr[16];
#pragma unroll
  for (int m = 0; m < 4; m++)
#pragma unroll
    for (int r = 0; r < 4; r++)
      biasr[m * 4 + r] = biasp[wr + m * 16 + lg * 4 + r];
  // direct [o][hw] stores, both segments
#pragma unroll
  for (int m = 0; m < 4; m++)
#pragma unroll
    for (int r = 0; r < 4; r++) {
      int ol = wr + m * 16 + lg * 4 + r;
      float bv_ = biasr[m * 4 + r];
#pragma unroll
      for (int n = 0; n < 4; n++) {
        Ob[(size_t)ol * kHW + bn0 + wc + n * 16 + lr] = f2b(acc0[m][n][r] + bv_);
        Ob[(size_t)ol * kHW + bn0 + 128 + wc + n * 16 + lr] = f2b(acc1[m][n][r] + bv_);
      }
    }
  if (bm < 512) {
    u16* Tb = f_chT + (size_t)b * kCHW;
    u16 (*T)[136] = (u16 (*)[136])smem;  // [128][136] = 34.8 KB
#pragma unroll 1
    for (int s = 0; s < 2; s++) {
      __syncthreads();
#pragma unroll
      for (int m = 0; m < 4; m++)
#pragma unroll
        for (int n = 0; n < 4; n++) {
          int ol = wr + m * 16 + lg * 4;
          int nl = wc + n * 16 + lr;
          us4 tv;
#pragma unroll
          for (int r = 0; r < 4; r++)
            tv[r] = f2b((s ? acc1[m][n][r] : acc0[m][n][r]) + biasr[m * 4 + r]);
          *(us4*)&T[nl][ol] = tv;
        }
      __syncthreads();
      int bn_ = bn0 + s * 128;
#pragma unroll
      for (int p = 0; p < 16; p++) {
        int ch = tid + p * 256;          // 4096 chunks: row = ch>>5, seg = ch&31
        int row = ch >> 5, seg = ch & 31;
        us4 v = *(const us4*)&T[row][seg * 4];
        *(us4*)&Tb[(size_t)(bn_ + row) * 512 + bm + seg * 4] = v;
      }
    }
  }
#undef F_STG
}

// ---------- Gram split-K, symmetric: only upper-tri tile pairs; mirror write ----------
__global__ __launch_bounds__(256) void k_gram_sk(const u16* __restrict__ F,
                                                 u16* __restrict__ part) {
  __shared__ u16 As[2][128][64];
  __shared__ u16 Bs[2][128][64];
  int z = blockIdx.z;
  int b = z & 3, s = z >> 2;
  int L = blockIdx.x;                     // 0..9 upper-tri pair index
  int bm = (int)((0x3221110000ull >> (4 * L)) & 15) * 128;
  int bn = (int)((0x3323213210ull >> (4 * L)) & 15) * 128;
  const u16* Asrc = F + (size_t)b * kCHW;
  const u16* Bsrc = Asrc;
  const int LDA = kHW, LDB = kHW;
  int kbeg = s * 1152;
  GEMM_PROLOG();
  PIPELOOP(18, kbeg);
  u16* Pb = part + ((size_t)(s * 4 + b)) * 262144;
#pragma unroll
  for (int m = 0; m < 4; m++)
#pragma unroll
    for (int n = 0; n < 4; n++) {
      us4 tv;
#pragma unroll
      for (int r = 0; r < 4; r++) {
        tv[r] = f2b(acc[m][n][r]);
        Pb[(size_t)(bm + wr + m * 16 + lg * 4 + r) * 512 + bn + wc + n * 16 + lr] = tv[r];
      }
      if (bm != bn)   // mirror tile: P[j][i] = P[i][j]
        *(us4*)&Pb[(size_t)(bn + wc + n * 16 + lr) * 512 + bm + wr + m * 16 + lg * 4] = tv;
    }
}

// ---------- out_C GEMM -> bf16 OutC[b][hw][c] (flat == d_out) ----------
__global__ __launch_bounds__(256) void k_outc(
    const u16* __restrict__ AT, const u16* __restrict__ Bt,
    const float* __restrict__ gamma, u16* __restrict__ Out) {
  __shared__ u16 As[2][128][64];
  __shared__ u16 Bs[2][128][64];
  int b = blockIdx.z;
  int bm = blockIdx.y * 128;   // hw
  int bn = blockIdx.x * 128;   // c
  const u16* Asrc = AT + (size_t)b * kCHW;
  const u16* Bsrc = Bt + (size_t)b * 262144;
  const int LDA = 512, LDB = 512;
  GEMM_PROLOG();
  PIPELOOP(8, 0);
  float g = *gamma;
  u16* Ob = Out + (size_t)b * kCHW;
#pragma unroll
  for (int m = 0; m < 4; m++)
#pragma unroll
    for (int r = 0; r < 4; r++) {
      int mm = bm + wr + m * 16 + lg * 4 + r;
#pragma unroll
      for (int n = 0; n < 4; n++)
        Ob[(size_t)mm * 512 + bn + wc + n * 16 + lr] = f2b(g * acc[m][n][r]);
    }
}

// ---------- 8-way bf16 partial reduce + row softmax over 512 -> gramN fp32 ----------
__global__ __launch_bounds__(256) void k_softmax512r(const u16* __restrict__ part,
                                                     float* __restrict__ gramN) {
  int b = blockIdx.x >> 9, i = blockIdx.x & 511;
  int tid = threadIdx.x;
  float v0 = 0.f, v1 = 0.f;
#pragma unroll
  for (int s = 0; s < 8; s++) {
    const u16* P = part + ((size_t)(s * 4 + b) * 512 + i) * 512;
    v0 += b2f(P[tid]);
    v1 += b2f(P[tid + 256]);
  }
  int wid = tid >> 6, lane = tid & 63;
  float m = fmaxf(v0, v1);
#pragma unroll
  for (int o = 32; o >= 1; o >>= 1) m = fmaxf(m, __shfl_xor(m, o));
  __shared__ float redm[4], reds[4];
  if (lane == 0) redm[wid] = m;
  __syncthreads();
  m = fmaxf(fmaxf(redm[0], redm[1]), fmaxf(redm[2], redm[3]));
  float e0 = expf(v0 - m), e1 = expf(v1 - m);
  float s = e0 + e1;
#pragma unroll
  for (int o = 32; o >= 1; o >>= 1) s += __shfl_xor(s, o);
  if (lane == 0) reds[wid] = s;
  __syncthreads();
  s = reds[0] + reds[1] + reds[2] + reds[3];
  float inv = 1.0f / s;
  float* R = gramN + ((size_t)b * 512 + i) * 512;
  R[tid] = e0 * inv;
  R[tid + 256] = e1 * inv;
}

// ---------- E_h -> ccat[b,i,w, j<96] (bf16 in/out) ----------
__global__ __launch_bounds__(256) void k_eh(
    const u16* __restrict__ fhw, u16* __restrict__ Ccat) {
  int b = blockIdx.x / kW, w = blockIdx.x % kW;
  __shared__ float fh[kH][kCr];
  __shared__ float fw[kCr][kH];
  int tid = threadIdx.x;
  for (int l = tid; l < kH * kCr; l += 256) {
    int i = l >> 3, c = l & 7;
    fh[i][c] = b2f(fhw[((size_t)b * 16 + (i & 7)) * kHW + (c * 12 + (i >> 3)) * kW + w]);
    int c2 = l / kH, j = l % kH;
    fw[c2][j] = b2f(fhw[((size_t)b * 16 + 8 + c2) * kHW + j * kW + w]);
  }
  __syncthreads();
  for (int t = tid; t < kH * kH; t += 256) {
    int i = t / kH, j = t % kH;
    float e = 0.f;
#pragma unroll
    for (int c = 0; c < kCr; c++) e += fh[i][c] * fw[c][j];
    if (i == j) e += NEGV;
    Ccat[(((size_t)b * kH + i) * kW + w) * 192 + j] = f2b(e);
  }
}

// ---------- E_w -> ccat[b,h,w, 96+j] (bf16 in/out) ----------
__global__ __launch_bounds__(256) void k_ew(
    const u16* __restrict__ fhw, u16* __restrict__ Ccat) {
  int b = blockIdx.x / kH, h = blockIdx.x % kH;
  __shared__ float fh2[kCr][kW];
  __shared__ float fw2[kCr][kW];
  int tid = threadIdx.x;
  for (int l = tid; l < kCr * kW; l += 256) {
    int c = l / kW, w = l % kW;
    fh2[c][w] = b2f(fhw[((size_t)b * 16 + c) * kHW + h * kW + w]);
    fw2[c][w] = b2f(fhw[((size_t)b * 16 + 8 + c) * kHW + h * kW + w]);
  }
  __syncthreads();
  for (int t = tid; t < kW * kW; t += 256) {
    int w = t / kW, j = t % kW;
    float e = 0.f;
#pragma unroll
    for (int c = 0; c < kCr; c++) e += fh2[c][w] * fw2[c][j];
    Ccat[(((size_t)b * kH + h) * kW + w) * 192 + 96 + j] = f2b(e);
  }
}

// ---------- softmax over 192 (bf16 in-place), one wave per row ----------
__global__ __launch_bounds__(256) void k_softmax192(u16* __restrict__ Ccat) {
  int r = blockIdx.x * 4 + (threadIdx.x >> 6);
  int lane = threadIdx.x & 63;
  u16* R = Ccat + (size_t)r * 192;
  float a = b2f(R[lane]), b = b2f(R[lane + 64]), c = b2f(R[lane + 128]);
  float m = fmaxf(a, fmaxf(b, c));
#pragma unroll
  for (int o = 32; o >= 1; o >>= 1) m = fmaxf(m, __shfl_xor(m, o));
  float ea = expf(a - m), eb = expf(b - m), ec = expf(c - m);
  float s = ea + eb + ec;
#pragma unroll
  for (int o = 32; o >= 1; o >>= 1) s += __shfl_xor(s, o);
  float inv = 1.0f / s;
  R[lane] = f2b(ea * inv);
  R[lane + 64] = f2b(eb * inv);
  R[lane + 128] = f2b(ec * inv);
}

// ---------- per-(b,c) 96x96 plane transpose (bf16) ----------
__global__ __launch_bounds__(256) void k_tr_plane(const u16* __restrict__ in,
                                                  u16* __restrict__ out) {
  size_t pl = blockIdx.x;
  const u16* ib = in + pl * 9216;
  u16* ob = out + pl * 9216;
  __shared__ u16 T[96][100];
  int tid = threadIdx.x;
  for (int ch = tid; ch < 96 * 24; ch += 256) {
    int i = ch / 24, seg = ch % 24;
    *(us4*)&T[i][seg*4] = *(const us4*)&ib[i*96 + seg*4];
  }
  __syncthreads();
  for (int ch = tid; ch < 96 * 24; ch += 256) {
    int j = ch / 24, seg = ch % 24;
    us4 o;
#pragma unroll
    for (int e = 0; e < 4; e++) o[e] = T[seg*4+e][j];
    *(us4*)&ob[j*96 + seg*4] = o;
  }
}

// ---------- H-path: per (b,w): HT[b][c][w][h] = alpha * sum_j AT[c][j] att[h][j] ----------
__global__ __launch_bounds__(512) void k_final_h(
    const u16* __restrict__ AT,    // f_chaT [B][512][96(w)][96(j=h)]
    const u16* __restrict__ att,   // ccat bf16 [B][96][96][192]
    const float* __restrict__ alpha,
    u16* __restrict__ OutHT) {
  int b = blockIdx.x / 96, w = blockIdx.x % 96;
  __shared__ u16 Bs[96][104];
  int tid = threadIdx.x;
  for (int ch = tid; ch < 1152; ch += 512) {
    int h = ch / 12, seg = ch % 12;
    *(short8*)&Bs[h][seg*8] =
        *(const short8*)&att[(((size_t)b*96 + h)*96 + w)*192 + seg*8];
  }
  __syncthreads();
  int lane = tid & 63, wv = tid >> 6;
  int lr = lane & 15, lg = lane >> 4;
  int c0 = wv * 64;
  const u16* Ab = AT + ((size_t)b*512 + c0)*kHW + w*96;
  f32x4 acc[4][6] = {};
#pragma unroll
  for (int ks = 0; ks < 3; ks++) {
    short8 av[4];
#pragma unroll
    for (int m = 0; m < 4; m++)
      av[m] = *(const short8*)&Ab[(size_t)(m*16 + lr)*kHW + ks*32 + lg*8];
#pragma unroll
    for (int n = 0; n < 6; n++) {
      short8 bv = *(const short8*)&Bs[n*16 + lr][ks*32 + lg*8];
#pragma unroll
      for (int m = 0; m < 4; m++) acc[m][n] = MFMA(av[m], bv, acc[m][n]);
    }
  }
  float al = *alpha;
  u16* Ob = OutHT + ((size_t)b*512 + c0)*kHW + w*96;
#pragma unroll
  for (int m = 0; m < 4; m++)
#pragma unroll
    for (int r = 0; r < 4; r++) {
      size_t crow = (size_t)(m*16 + lg*4 + r) * kHW;
#pragma unroll
      for (int n = 0; n < 6; n++)
        Ob[crow + n*16 + lr] = f2b(al * acc[m][n][r]);
    }
}

// ---------- W-path: per (b,h): OutW[b][c][h][w] = beta * sum_j A[c][j] att[w][96+j] ----------
__global__ __launch_bounds__(512) void k_final_w(
    const u16* __restrict__ A,     // f_cha [B][512][96(h)][96(j=w)]
    const u16* __restrict__ att,
    const float* __restrict__ beta,
    u16* __restrict__ OutW) {
  int b = blockIdx.x / 96, h = blockIdx.x % 96;
  __shared__ u16 Bs[96][104];
  int tid = threadIdx.x;
  for (int ch = tid; ch < 1152; ch += 512) {
    int wr_ = ch / 12, seg = ch % 12;
    *(short8*)&Bs[wr_][seg*8] =
        *(const short8*)&att[(((size_t)b*96 + h)*96 + wr_)*192 + 96 + seg*8];
  }
  __syncthreads();
  int lane = tid & 63, wv = tid >> 6;
  int lr = lane & 15, lg = lane >> 4;
  int c0 = wv * 64;
  const u16* Ab = A + ((size_t)b*512 + c0)*kHW + h*96;
  f32x4 acc[4][6] = {};
#pragma unroll
  for (int ks = 0; ks < 3; ks++) {
    short8 av[4];
#pragma unroll
    for (int m = 0; m < 4; m++)
      av[m] = *(const short8*)&Ab[(size_t)(m*16 + lr)*kHW + ks*32 + lg*8];
#pragma unroll
    for (int n = 0; n < 6; n++) {
      short8 bv = *(const short8*)&Bs[n*16 + lr][ks*32 + lg*8];
#pragma unroll
      for (int m = 0; m < 4; m++) acc[m][n] = MFMA(av[m], bv, acc[m][n]);
    }
  }
  float be = *beta;
  u16* Ob = OutW + ((size_t)b*512 + c0)*kHW + h*96;
#pragma unroll
  for (int m = 0; m < 4; m++)
#pragma unroll
    for (int r = 0; r < 4; r++) {
      size_t crow = (size_t)(m*16 + lg*4 + r) * kHW;
#pragma unroll
      for (int n = 0; n < 6; n++)
        Ob[crow + n*16 + lr] = f2b(be * acc[m][n][r]);
    }
}

// ---------- merge: out = x + OutC + OutW + HT^T(per plane) ----------
__global__ __launch_bounds__(256) void k_merge(
    const float* __restrict__ x, const u16* __restrict__ OutC,
    const u16* __restrict__ OutW, const u16* __restrict__ HT,
    float* __restrict__ out) {
  size_t pl = blockIdx.x;
  const u16* hb = HT + pl * 9216;
  __shared__ u16 T[96][100];
  int tid = threadIdx.x;
  for (int ch = tid; ch < 96 * 24; ch += 256) {
    int i = ch / 24, seg = ch % 24;
    *(us4*)&T[i][seg*4] = *(const us4*)&hb[i*96 + seg*4];
  }
  __syncthreads();
  const float* xb = x + pl * 9216;
  const u16* cb = OutC + pl * 9216;
  const u16* wb = OutW + pl * 9216;
  float* ob = out + pl * 9216;
  for (int ch = tid; ch < 2304; ch += 256) {
    int i4 = ch * 4;
    int h = i4 / 96, w = i4 % 96;
    f32x4 xv = *(const f32x4*)&xb[i4];
    us4 cv = *(const us4*)&cb[i4];
    us4 wv = *(const us4*)&wb[i4];
    f32x4 o;
#pragma unroll
    for (int e = 0; e < 4; e++)
      o[e] = xv[e] + b2f(cv[e]) + b2f(wv[e]) + b2f(T[w + e][h]);
    *(f32x4*)&ob[i4] = o;
  }
}

extern "C" void kernel_launch(void* const* d_in, const int* in_sizes, int n_in,
                              void* d_out, int out_size, void* d_ws, size_t ws_size,
                              hipStream_t stream) {
  const float* x     = (const float*)d_in[0];
  const float* w_h   = (const float*)d_in[1];
  const float* b_h   = (const float*)d_in[2];
  const float* w_w   = (const float*)d_in[3];
  const float* b_w   = (const float*)d_in[4];
  const float* w_c   = (const float*)d_in[5];
  const float* b_c   = (const float*)d_in[6];
  const float* w_o   = (const float*)d_in[7];
  const float* b_o   = (const float*)d_in[8];
  const float* alpha = (const float*)d_in[9];
  const float* beta  = (const float*)d_in[10];
  const float* gamma = (const float*)d_in[11];
  float* out = (float*)d_out;

  const size_t R = 37748736;
  char* p = (char*)d_ws;
  u16*   xbfT   = (u16*)(p);
  u16*   part   = (u16*)(p);
  u16*   f_chaT = (u16*)(p);
  u16*   outW   = (u16*)(p);
  u16*   f_ch   = (u16*)(p + R);
  u16*   outC   = (u16*)(p + R);
  u16*   f_chT  = (u16*)(p + 2 * R);
  u16*   outHT  = (u16*)(p + 2 * R);
  u16*   f_cha  = (u16*)(p + 3 * R);
  u16*   fhw    = (u16*)(p + 4 * R);
  char*  F      = p + 4 * R + 2359296;
  float* gramN  = (float*)F;
  u16*   affT   = (u16*)(F + 4194304);
  u16*   ccat   = (u16*)F;
  u16*   wco    = (u16*)(F + 14155776);

  k_cvt_T<<<dim3(144, 8, 4), 256, 0, stream>>>(x, xbfT, 512, 9216);
  k_cvtw<<<512, 256, 0, stream>>>(w_c, w_o, wco);
  k_conv16<<<dim3(72, 4), 256, 0, stream>>>(w_h, b_h, w_w, b_w, xbfT, fhw);
  k_gemm_conv2<<<dim3(36, 8, 4), 256, 0, stream>>>(wco, xbfT, b_c, b_o, f_ch, f_cha, f_chT);
  k_gram_sk<<<dim3(10, 1, 32), 256, 0, stream>>>(f_ch, part);
  k_softmax512r<<<2048, 256, 0, stream>>>(part, gramN);
  k_cvt_T<<<dim3(8, 8, 4), 256, 0, stream>>>(gramN, affT, 512, 512);
  k_outc<<<dim3(4, 72, 4), 256, 0, stream>>>(f_chT, affT, gamma, outC);
  k_eh<<<384, 256, 0, stream>>>(fhw, ccat);
  k_ew<<<384, 256, 0, stream>>>(fhw, ccat);
  k_softmax192<<<9216, 256, 0, stream>>>(ccat);
  k_tr_plane<<<2048, 256, 0, stream>>>(f_cha, f_chaT);
  k_final_h<<<384, 512, 0, stream>>>(f_chaT, ccat, alpha, outHT);
  k_final_w<<<384, 512, 0, stream>>>(f_cha, ccat, beta, outW);
  k_merge<<<2048, 256, 0, stream>>>(x, outC, outW, outHT, out);
}

// Round 11
// 293.274 us; speedup vs baseline: 1.0856x; 1.0856x over previous
//
#include <hip/hip_runtime.h>

typedef __attribute__((ext_vector_type(8))) short short8;
typedef __attribute__((ext_vector_type(4))) float f32x4;
typedef __attribute__((ext_vector_type(4))) unsigned short us4;
typedef unsigned short u16;

#define kB 4
#define kC 512
#define kCr 8
#define kH 96
#define kW 96
#define kHW 9216
#define kCHW 4718592
#define NEGV -1e9f

__device__ __forceinline__ u16 f2b(float f) {
  union { float f; unsigned u; } v; v.f = f;
  unsigned r = v.u + 0x7fff + ((v.u >> 16) & 1);
  return (u16)(r >> 16);
}
__device__ __forceinline__ float b2f(u16 h) {
  union { unsigned u; float f; } v; v.u = ((unsigned)h) << 16;
  return v.f;
}
#define MFMA(a, b, c) __builtin_amdgcn_mfma_f32_16x16x32_bf16(a, b, c, 0, 0, 0)

// async global->LDS, 16B per lane. LDS dest must be wave-uniform-base + lane*16.
__device__ __forceinline__ void gl16(const u16* g, u16* l) {
  __builtin_amdgcn_global_load_lds(
      (const __attribute__((address_space(1))) void*)g,
      (__attribute__((address_space(3))) void*)l, 16, 0, 0);
}

// ---------- fp32 [R][C] -> bf16 [C][R] transpose-convert, 64x64 tiles ----------
__global__ __launch_bounds__(256) void k_cvt_T(const float* __restrict__ in,
                                               u16* __restrict__ out,
                                               int R, int C) {
  const float* ib = in + (size_t)blockIdx.z * R * C;
  u16* ob = out + (size_t)blockIdx.z * R * C;
  int c0 = blockIdx.x * 64, r0 = blockIdx.y * 64;
  __shared__ u16 T[64][68];
  int tid = threadIdx.x;
#pragma unroll
  for (int p = 0; p < 4; p++) {
    int ch = tid + p * 256;
    int i = ch >> 4, seg = ch & 15;
    f32x4 v = *(const f32x4*)&ib[(size_t)(r0 + i) * C + c0 + seg * 4];
    T[i][seg*4+0] = f2b(v[0]); T[i][seg*4+1] = f2b(v[1]);
    T[i][seg*4+2] = f2b(v[2]); T[i][seg*4+3] = f2b(v[3]);
  }
  __syncthreads();
#pragma unroll
  for (int p = 0; p < 4; p++) {
    int ch = tid + p * 256;
    int j = ch >> 4, seg = ch & 15;
    us4 o;
#pragma unroll
    for (int e = 0; e < 4; e++) o[e] = T[seg*4+e][j];
    *(us4*)&ob[(size_t)(c0 + j) * R + r0 + seg * 4] = o;
  }
}

// ---------- weights fp32 -> bf16: wco[0:512]=w_c, wco[512:1024]=w_o ----------
__global__ __launch_bounds__(256) void k_cvtw(const float* __restrict__ wc,
                                              const float* __restrict__ wo,
                                              u16* __restrict__ wco) {
  int i = blockIdx.x * 256 + threadIdx.x;   // 131072 chunks of 4 floats
  const float* src = (i < 65536) ? &wc[(size_t)i * 4] : &wo[(size_t)(i - 65536) * 4];
  f32x4 v = *(const f32x4*)src;
  us4 o;
  o[0] = f2b(v[0]); o[1] = f2b(v[1]); o[2] = f2b(v[2]); o[3] = f2b(v[3]);
  ((us4*)wco)[i] = o;
}

// ---------- small convs via MFMA: fhw[b][r][hw], r<8: w_h conv, r>=8: w_w conv ----------
__global__ __launch_bounds__(256) void k_conv16(
    const float* __restrict__ wh, const float* __restrict__ bh,
    const float* __restrict__ ww, const float* __restrict__ bw,
    const u16* __restrict__ XT, u16* __restrict__ Out) {
  __shared__ u16 As[16][520];
  __shared__ float bias_s[16];
  int tid = threadIdx.x;
#pragma unroll
  for (int p = 0; p < 4; p++) {
    int ch = tid + p * 256;               // 1024 chunks of 8 elems
    int r = ch >> 6, seg = ch & 63;
    const float* src = (r < 8) ? &wh[r * 512 + seg * 8] : &ww[(r - 8) * 512 + seg * 8];
    f32x4 v0 = *(const f32x4*)src;
    f32x4 v1 = *(const f32x4*)(src + 4);
    short8 sv;
    sv[0]=f2b(v0[0]); sv[1]=f2b(v0[1]); sv[2]=f2b(v0[2]); sv[3]=f2b(v0[3]);
    sv[4]=f2b(v1[0]); sv[5]=f2b(v1[1]); sv[6]=f2b(v1[2]); sv[7]=f2b(v1[3]);
    *(short8*)&As[r][seg * 8] = sv;
  }
  if (tid < 16) bias_s[tid] = (tid < 8) ? bh[tid] : bw[tid - 8];
  __syncthreads();
  int b = blockIdx.y;
  int nb = blockIdx.x * 128 + (tid >> 6) * 32;   // wave's 32-n strip
  int lane = tid & 63;
  int lr = lane & 15, lg = lane >> 4;
  const u16* Bb = XT + (size_t)b * kCHW;
  f32x4 acc[2] = {};
#pragma unroll 4
  for (int k0 = 0; k0 < 512; k0 += 32) {
    short8 a = *(const short8*)&As[lr][k0 + lg * 8];
    short8 b0 = *(const short8*)&Bb[(size_t)(nb + lr) * 512 + k0 + lg * 8];
    short8 b1 = *(const short8*)&Bb[(size_t)(nb + 16 + lr) * 512 + k0 + lg * 8];
    acc[0] = MFMA(a, b0, acc[0]);
    acc[1] = MFMA(a, b1, acc[1]);
  }
#pragma unroll
  for (int q = 0; q < 2; q++)
#pragma unroll
    for (int r = 0; r < 4; r++) {
      int m = lg * 4 + r;
      Out[((size_t)b * 16 + m) * kHW + nb + q * 16 + lr] = f2b(acc[q][r] + bias_s[m]);
    }
}

// ======== shared pipelined 128x128 GEMM pieces (A.B^T, K-major rows) ========
// LDS linear [2][128][64], gload_lds staging, XOR chunk-swizzle both sides.
// Counted-vmcnt: loads for tile t+1 stay in flight across barriers.
#define GEMM_PROLOG()                                                      \
  int tid = threadIdx.x;                                                   \
  int lane = tid & 63, wv = tid >> 6;                                      \
  int wr = (wv >> 1) * 64, wc = (wv & 1) * 64;                             \
  int lr = lane & 15, lg = lane >> 4;                                      \
  f32x4 acc[4][4] = {};

#define STAGE(bufv, kk)                                                    \
  {                                                                        \
    _Pragma("unroll")                                                      \
    for (int p = 0; p < 4; p++) {                                          \
      int ch = tid + p * 256;                                              \
      int row = ch >> 3, cc = ch & 7;                                      \
      int sc = (cc ^ (row & 7)) * 8;                                       \
      gl16(&Asrc[(size_t)(bm + row) * LDA + (kk) + sc], &As[bufv][row][cc * 8]); \
      gl16(&Bsrc[(size_t)(bn + row) * LDB + (kk) + sc], &Bs[bufv][row][cc * 8]); \
    }                                                                      \
  }

#define COMPUTE(bufv)                                                      \
  {                                                                        \
    _Pragma("unroll")                                                      \
    for (int ks = 0; ks < 2; ks++) {                                       \
      int ca = ((ks * 4 + lg) ^ (lr & 7)) * 8;                             \
      short8 av[4], bv[4];                                                 \
      _Pragma("unroll")                                                    \
      for (int m = 0; m < 4; m++)                                          \
        av[m] = *(const short8*)&As[bufv][wr + m * 16 + lr][ca];           \
      _Pragma("unroll")                                                    \
      for (int n = 0; n < 4; n++)                                          \
        bv[n] = *(const short8*)&Bs[bufv][wc + n * 16 + lr][ca];           \
      __builtin_amdgcn_s_setprio(1);                                       \
      _Pragma("unroll")                                                    \
      for (int m = 0; m < 4; m++)                                          \
        _Pragma("unroll")                                                  \
        for (int n = 0; n < 4; n++)                                        \
          acc[m][n] = MFMA(av[m], bv[n], acc[m][n]);                       \
      __builtin_amdgcn_s_setprio(0);                                       \
    }                                                                      \
  }

#define VMBAR(N)                                                           \
  asm volatile("s_waitcnt vmcnt(" #N ")" ::: "memory");                    \
  __builtin_amdgcn_s_barrier();

#define LGBAR                                                              \
  asm volatile("s_waitcnt lgkmcnt(0)" ::: "memory");                       \
  __builtin_amdgcn_s_barrier();

// plain NT-tile pipeline (single output tile)
#define PIPELOOP(NT, KBASE)                                                \
  STAGE(0, (KBASE));                                                       \
  STAGE(1, (KBASE) + 64);                                                  \
  {                                                                        \
    int cur = 0;                                                           \
    _Pragma("unroll 1")                                                    \
    for (int t = 0; t < (NT) - 2; t++) {                                   \
      VMBAR(8);                                                            \
      COMPUTE(cur);                                                        \
      LGBAR;                                                               \
      STAGE(cur, (KBASE) + (t + 2) * 64);                                  \
      cur ^= 1;                                                            \
    }                                                                      \
    VMBAR(8);                                                              \
    COMPUTE(cur);                                                          \
    cur ^= 1;                                                              \
    VMBAR(0);                                                              \
    COMPUTE(cur);                                                          \
  }

// ---------- merged conv1x1 GEMM (R8 configuration) + LDS-transposed f_chT epilogue ----------
// For bm<512 (w_c half) also writes f_chT[hw][o] via full-line coalesced stores.
__global__ __launch_bounds__(256) void k_gemm_conv2(
    const u16* __restrict__ wco, const u16* __restrict__ BT,
    const float* __restrict__ b_c, const float* __restrict__ b_o,
    u16* __restrict__ f_ch, u16* __restrict__ f_cha, u16* __restrict__ f_chT) {
  __shared__ u16 smem[32768];   // 64 KB: [2][128][64] As + [2][128][64] Bs, reused as T
  u16 (*As)[128][64] = (u16 (*)[128][64])smem;
  u16 (*Bs)[128][64] = (u16 (*)[128][64])(smem + 16384);
  int b = blockIdx.z;
  int bm = blockIdx.y * 128;   // o in [0,1024)
  int bn = blockIdx.x * 128;   // hw
  const u16* Asrc = wco;
  const u16* Bsrc = BT + (size_t)b * kCHW;
  const int LDA = 512, LDB = 512;
  GEMM_PROLOG();
  PIPELOOP(8, 0);
  const float* biasp = (bm < 512) ? (b_c + bm) : (b_o + bm - 512);
  u16* Ob = (bm < 512) ? (f_ch + (size_t)b * kCHW + (size_t)bm * kHW)
                       : (f_cha + (size_t)b * kCHW + (size_t)(bm - 512) * kHW);
#pragma unroll
  for (int m = 0; m < 4; m++)
#pragma unroll
    for (int r = 0; r < 4; r++) {
      int ol = wr + m * 16 + lg * 4 + r;
      float bv_ = biasp[ol];
#pragma unroll
      for (int n = 0; n < 4; n++)
        Ob[(size_t)ol * kHW + bn + wc + n * 16 + lr] = f2b(acc[m][n][r] + bv_);
    }
  if (bm < 512) {
    // LDS transpose: T[n_local][o_local], rows padded to 136
    __syncthreads();               // staging LDS no longer needed
    u16 (*T)[136] = (u16 (*)[136])smem;
#pragma unroll
    for (int m = 0; m < 4; m++)
#pragma unroll
      for (int n = 0; n < 4; n++) {
        int ol = wr + m * 16 + lg * 4;
        float bv0 = biasp[ol], bv1 = biasp[ol+1], bv2 = biasp[ol+2], bv3 = biasp[ol+3];
        int nl = wc + n * 16 + lr;
        T[nl][ol + 0] = f2b(acc[m][n][0] + bv0);
        T[nl][ol + 1] = f2b(acc[m][n][1] + bv1);
        T[nl][ol + 2] = f2b(acc[m][n][2] + bv2);
        T[nl][ol + 3] = f2b(acc[m][n][3] + bv3);
      }
    __syncthreads();
    u16* Tb = f_chT + (size_t)b * kCHW;
#pragma unroll
    for (int p = 0; p < 16; p++) {
      int ch = tid + p * 256;          // 4096 chunks: row = ch>>5, seg = ch&31
      int row = ch >> 5, seg = ch & 31;
      us4 v = *(const us4*)&T[row][seg * 4];
      *(us4*)&Tb[(size_t)(bn + row) * 512 + bm + seg * 4] = v;
    }
  }
}

// ---------- Gram split-K, symmetric: only upper-tri tile pairs; mirror write ----------
__global__ __launch_bounds__(256) void k_gram_sk(const u16* __restrict__ F,
                                                 u16* __restrict__ part) {
  __shared__ u16 As[2][128][64];
  __shared__ u16 Bs[2][128][64];
  int z = blockIdx.z;
  int b = z & 3, s = z >> 2;
  int L = blockIdx.x;                     // 0..9 upper-tri pair index
  int bm = (int)((0x3221110000ull >> (4 * L)) & 15) * 128;
  int bn = (int)((0x3323213210ull >> (4 * L)) & 15) * 128;
  const u16* Asrc = F + (size_t)b * kCHW;
  const u16* Bsrc = Asrc;
  const int LDA = kHW, LDB = kHW;
  int kbeg = s * 1152;
  GEMM_PROLOG();
  PIPELOOP(18, kbeg);
  u16* Pb = part + ((size_t)(s * 4 + b)) * 262144;
#pragma unroll
  for (int m = 0; m < 4; m++)
#pragma unroll
    for (int n = 0; n < 4; n++) {
      us4 tv;
#pragma unroll
      for (int r = 0; r < 4; r++) {
        tv[r] = f2b(acc[m][n][r]);
        Pb[(size_t)(bm + wr + m * 16 + lg * 4 + r) * 512 + bn + wc + n * 16 + lr] = tv[r];
      }
      if (bm != bn)   // mirror tile: P[j][i] = P[i][j]
        *(us4*)&Pb[(size_t)(bn + wc + n * 16 + lr) * 512 + bm + wr + m * 16 + lg * 4] = tv;
    }
}

// ---------- out_C GEMM -> bf16 OutC[b][hw][c] (flat == d_out) ----------
__global__ __launch_bounds__(256) void k_outc(
    const u16* __restrict__ AT, const u16* __restrict__ Bt,
    const float* __restrict__ gamma, u16* __restrict__ Out) {
  __shared__ u16 As[2][128][64];
  __shared__ u16 Bs[2][128][64];
  int b = blockIdx.z;
  int bm = blockIdx.y * 128;   // hw
  int bn = blockIdx.x * 128;   // c
  const u16* Asrc = AT + (size_t)b * kCHW;
  const u16* Bsrc = Bt + (size_t)b * 262144;
  const int LDA = 512, LDB = 512;
  GEMM_PROLOG();
  PIPELOOP(8, 0);
  float g = *gamma;
  u16* Ob = Out + (size_t)b * kCHW;
#pragma unroll
  for (int m = 0; m < 4; m++)
#pragma unroll
    for (int r = 0; r < 4; r++) {
      int mm = bm + wr + m * 16 + lg * 4 + r;
#pragma unroll
      for (int n = 0; n < 4; n++)
        Ob[(size_t)mm * 512 + bn + wc + n * 16 + lr] = f2b(g * acc[m][n][r]);
    }
}

// ---------- 8-way bf16 partial reduce + row softmax over 512 -> gramN fp32 ----------
__global__ __launch_bounds__(256) void k_softmax512r(const u16* __restrict__ part,
                                                     float* __restrict__ gramN) {
  int b = blockIdx.x >> 9, i = blockIdx.x & 511;
  int tid = threadIdx.x;
  float v0 = 0.f, v1 = 0.f;
#pragma unroll
  for (int s = 0; s < 8; s++) {
    const u16* P = part + ((size_t)(s * 4 + b) * 512 + i) * 512;
    v0 += b2f(P[tid]);
    v1 += b2f(P[tid + 256]);
  }
  int wid = tid >> 6, lane = tid & 63;
  float m = fmaxf(v0, v1);
#pragma unroll
  for (int o = 32; o >= 1; o >>= 1) m = fmaxf(m, __shfl_xor(m, o));
  __shared__ float redm[4], reds[4];
  if (lane == 0) redm[wid] = m;
  __syncthreads();
  m = fmaxf(fmaxf(redm[0], redm[1]), fmaxf(redm[2], redm[3]));
  float e0 = expf(v0 - m), e1 = expf(v1 - m);
  float s = e0 + e1;
#pragma unroll
  for (int o = 32; o >= 1; o >>= 1) s += __shfl_xor(s, o);
  if (lane == 0) reds[wid] = s;
  __syncthreads();
  s = reds[0] + reds[1] + reds[2] + reds[3];
  float inv = 1.0f / s;
  float* R = gramN + ((size_t)b * 512 + i) * 512;
  R[tid] = e0 * inv;
  R[tid + 256] = e1 * inv;
}

// ---------- E_h -> ccat[b,i,w, j<96] (bf16 in/out) ----------
__global__ __launch_bounds__(256) void k_eh(
    const u16* __restrict__ fhw, u16* __restrict__ Ccat) {
  int b = blockIdx.x / kW, w = blockIdx.x % kW;
  __shared__ float fh[kH][kCr];
  __shared__ float fw[kCr][kH];
  int tid = threadIdx.x;
  for (int l = tid; l < kH * kCr; l += 256) {
    int i = l >> 3, c = l & 7;
    fh[i][c] = b2f(fhw[((size_t)b * 16 + (i & 7)) * kHW + (c * 12 + (i >> 3)) * kW + w]);
    int c2 = l / kH, j = l % kH;
    fw[c2][j] = b2f(fhw[((size_t)b * 16 + 8 + c2) * kHW + j * kW + w]);
  }
  __syncthreads();
  for (int t = tid; t < kH * kH; t += 256) {
    int i = t / kH, j = t % kH;
    float e = 0.f;
#pragma unroll
    for (int c = 0; c < kCr; c++) e += fh[i][c] * fw[c][j];
    if (i == j) e += NEGV;
    Ccat[(((size_t)b * kH + i) * kW + w) * 192 + j] = f2b(e);
  }
}

// ---------- E_w -> ccat[b,h,w, 96+j] (bf16 in/out) ----------
__global__ __launch_bounds__(256) void k_ew(
    const u16* __restrict__ fhw, u16* __restrict__ Ccat) {
  int b = blockIdx.x / kH, h = blockIdx.x % kH;
  __shared__ float fh2[kCr][kW];
  __shared__ float fw2[kCr][kW];
  int tid = threadIdx.x;
  for (int l = tid; l < kCr * kW; l += 256) {
    int c = l / kW, w = l % kW;
    fh2[c][w] = b2f(fhw[((size_t)b * 16 + c) * kHW + h * kW + w]);
    fw2[c][w] = b2f(fhw[((size_t)b * 16 + 8 + c) * kHW + h * kW + w]);
  }
  __syncthreads();
  for (int t = tid; t < kW * kW; t += 256) {
    int w = t / kW, j = t % kW;
    float e = 0.f;
#pragma unroll
    for (int c = 0; c < kCr; c++) e += fh2[c][w] * fw2[c][j];
    Ccat[(((size_t)b * kH + h) * kW + w) * 192 + 96 + j] = f2b(e);
  }
}

// ---------- softmax over 192 (bf16 in-place), one wave per row ----------
__global__ __launch_bounds__(256) void k_softmax192(u16* __restrict__ Ccat) {
  int r = blockIdx.x * 4 + (threadIdx.x >> 6);
  int lane = threadIdx.x & 63;
  u16* R = Ccat + (size_t)r * 192;
  float a = b2f(R[lane]), b = b2f(R[lane + 64]), c = b2f(R[lane + 128]);
  float m = fmaxf(a, fmaxf(b, c));
#pragma unroll
  for (int o = 32; o >= 1; o >>= 1) m = fmaxf(m, __shfl_xor(m, o));
  float ea = expf(a - m), eb = expf(b - m), ec = expf(c - m);
  float s = ea + eb + ec;
#pragma unroll
  for (int o = 32; o >= 1; o >>= 1) s += __shfl_xor(s, o);
  float inv = 1.0f / s;
  R[lane] = f2b(ea * inv);
  R[lane + 64] = f2b(eb * inv);
  R[lane + 128] = f2b(ec * inv);
}

// ---------- per-(b,c) 96x96 plane transpose (bf16) ----------
__global__ __launch_bounds__(256) void k_tr_plane(const u16* __restrict__ in,
                                                  u16* __restrict__ out) {
  size_t pl = blockIdx.x;
  const u16* ib = in + pl * 9216;
  u16* ob = out + pl * 9216;
  __shared__ u16 T[96][100];
  int tid = threadIdx.x;
  for (int ch = tid; ch < 96 * 24; ch += 256) {
    int i = ch / 24, seg = ch % 24;
    *(us4*)&T[i][seg*4] = *(const us4*)&ib[i*96 + seg*4];
  }
  __syncthreads();
  for (int ch = tid; ch < 96 * 24; ch += 256) {
    int j = ch / 24, seg = ch % 24;
    us4 o;
#pragma unroll
    for (int e = 0; e < 4; e++) o[e] = T[seg*4+e][j];
    *(us4*)&ob[j*96 + seg*4] = o;
  }
}

// ---------- H-path: per (b,w): HT[b][c][w][h] = alpha * sum_j AT[c][j] att[h][j] ----------
__global__ __launch_bounds__(512) void k_final_h(
    const u16* __restrict__ AT,    // f_chaT [B][512][96(w)][96(j=h)]
    const u16* __restrict__ att,   // ccat bf16 [B][96][96][192]
    const float* __restrict__ alpha,
    u16* __restrict__ OutHT) {
  int b = blockIdx.x / 96, w = blockIdx.x % 96;
  __shared__ u16 Bs[96][104];
  int tid = threadIdx.x;
  for (int ch = tid; ch < 1152; ch += 512) {
    int h = ch / 12, seg = ch % 12;
    *(short8*)&Bs[h][seg*8] =
        *(const short8*)&att[(((size_t)b*96 + h)*96 + w)*192 + seg*8];
  }
  __syncthreads();
  int lane = tid & 63, wv = tid >> 6;
  int lr = lane & 15, lg = lane >> 4;
  int c0 = wv * 64;
  const u16* Ab = AT + ((size_t)b*512 + c0)*kHW + w*96;
  f32x4 acc[4][6] = {};
#pragma unroll
  for (int ks = 0; ks < 3; ks++) {
    short8 av[4];
#pragma unroll
    for (int m = 0; m < 4; m++)
      av[m] = *(const short8*)&Ab[(size_t)(m*16 + lr)*kHW + ks*32 + lg*8];
#pragma unroll
    for (int n = 0; n < 6; n++) {
      short8 bv = *(const short8*)&Bs[n*16 + lr][ks*32 + lg*8];
#pragma unroll
      for (int m = 0; m < 4; m++) acc[m][n] = MFMA(av[m], bv, acc[m][n]);
    }
  }
  float al = *alpha;
  u16* Ob = OutHT + ((size_t)b*512 + c0)*kHW + w*96;
#pragma unroll
  for (int m = 0; m < 4; m++)
#pragma unroll
    for (int r = 0; r < 4; r++) {
      size_t crow = (size_t)(m*16 + lg*4 + r) * kHW;
#pragma unroll
      for (int n = 0; n < 6; n++)
        Ob[crow + n*16 + lr] = f2b(al * acc[m][n][r]);
    }
}

// ---------- W-path: per (b,h): OutW[b][c][h][w] = beta * sum_j A[c][j] att[w][96+j] ----------
__global__ __launch_bounds__(512) void k_final_w(
    const u16* __restrict__ A,     // f_cha [B][512][96(h)][96(j=w)]
    const u16* __restrict__ att,
    const float* __restrict__ beta,
    u16* __restrict__ OutW) {
  int b = blockIdx.x / 96, h = blockIdx.x % 96;
  __shared__ u16 Bs[96][104];
  int tid = threadIdx.x;
  for (int ch = tid; ch < 1152; ch += 512) {
    int wr_ = ch / 12, seg = ch % 12;
    *(short8*)&Bs[wr_][seg*8] =
        *(const short8*)&att[(((size_t)b*96 + h)*96 + wr_)*192 + 96 + seg*8];
  }
  __syncthreads();
  int lane = tid & 63, wv = tid >> 6;
  int lr = lane & 15, lg = lane >> 4;
  int c0 = wv * 64;
  const u16* Ab = A + ((size_t)b*512 + c0)*kHW + h*96;
  f32x4 acc[4][6] = {};
#pragma unroll
  for (int ks = 0; ks < 3; ks++) {
    short8 av[4];
#pragma unroll
    for (int m = 0; m < 4; m++)
      av[m] = *(const short8*)&Ab[(size_t)(m*16 + lr)*kHW + ks*32 + lg*8];
#pragma unroll
    for (int n = 0; n < 6; n++) {
      short8 bv = *(const short8*)&Bs[n*16 + lr][ks*32 + lg*8];
#pragma unroll
      for (int m = 0; m < 4; m++) acc[m][n] = MFMA(av[m], bv, acc[m][n]);
    }
  }
  float be = *beta;
  u16* Ob = OutW + ((size_t)b*512 + c0)*kHW + h*96;
#pragma unroll
  for (int m = 0; m < 4; m++)
#pragma unroll
    for (int r = 0; r < 4; r++) {
      size_t crow = (size_t)(m*16 + lg*4 + r) * kHW;
#pragma unroll
      for (int n = 0; n < 6; n++)
        Ob[crow + n*16 + lr] = f2b(be * acc[m][n][r]);
    }
}

// ---------- merge: out = x + OutC + OutW + HT^T(per plane) ----------
__global__ __launch_bounds__(256) void k_merge(
    const float* __restrict__ x, const u16* __restrict__ OutC,
    const u16* __restrict__ OutW, const u16* __restrict__ HT,
    float* __restrict__ out) {
  size_t pl = blockIdx.x;
  const u16* hb = HT + pl * 9216;
  __shared__ u16 T[96][100];
  int tid = threadIdx.x;
  for (int ch = tid; ch < 96 * 24; ch += 256) {
    int i = ch / 24, seg = ch % 24;
    *(us4*)&T[i][seg*4] = *(const us4*)&hb[i*96 + seg*4];
  }
  __syncthreads();
  const float* xb = x + pl * 9216;
  const u16* cb = OutC + pl * 9216;
  const u16* wb = OutW + pl * 9216;
  float* ob = out + pl * 9216;
  for (int ch = tid; ch < 2304; ch += 256) {
    int i4 = ch * 4;
    int h = i4 / 96, w = i4 % 96;
    f32x4 xv = *(const f32x4*)&xb[i4];
    us4 cv = *(const us4*)&cb[i4];
    us4 wv = *(const us4*)&wb[i4];
    f32x4 o;
#pragma unroll
    for (int e = 0; e < 4; e++)
      o[e] = xv[e] + b2f(cv[e]) + b2f(wv[e]) + b2f(T[w + e][h]);
    *(f32x4*)&ob[i4] = o;
  }
}

extern "C" void kernel_launch(void* const* d_in, const int* in_sizes, int n_in,
                              void* d_out, int out_size, void* d_ws, size_t ws_size,
                              hipStream_t stream) {
  const float* x     = (const float*)d_in[0];
  const float* w_h   = (const float*)d_in[1];
  const float* b_h   = (const float*)d_in[2];
  const float* w_w   = (const float*)d_in[3];
  const float* b_w   = (const float*)d_in[4];
  const float* w_c   = (const float*)d_in[5];
  const float* b_c   = (const float*)d_in[6];
  const float* w_o   = (const float*)d_in[7];
  const float* b_o   = (const float*)d_in[8];
  const float* alpha = (const float*)d_in[9];
  const float* beta  = (const float*)d_in[10];
  const float* gamma = (const float*)d_in[11];
  float* out = (float*)d_out;

  // Region plan. R = 37748736 (one [B][512][9216] bf16 buffer).
  //  A [0,R):   xbfT (1-3) / gram partials bf16 16.8MB (4-5) / f_chaT (11-12) / OutW (13-14)
  //  B [R,2R):  f_ch (3-4) / OutC (7-14)
  //  C [2R,3R): f_chT (3-7) / HT (12-14)
  //  D [3R,4R): f_cha (3-13)
  //  E: fhw bf16 [B][16][9216] (2-9)
  //  F: gramN(4.19M,5-6)+affT(2.10M,6-7) overlaid by ccat 14.16M (8-13); wco after ccat (1-3)
  const size_t R = 37748736;
  char* p = (char*)d_ws;
  u16*   xbfT   = (u16*)(p);
  u16*   part   = (u16*)(p);
  u16*   f_chaT = (u16*)(p);
  u16*   outW   = (u16*)(p);
  u16*   f_ch   = (u16*)(p + R);
  u16*   outC   = (u16*)(p + R);
  u16*   f_chT  = (u16*)(p + 2 * R);
  u16*   outHT  = (u16*)(p + 2 * R);
  u16*   f_cha  = (u16*)(p + 3 * R);
  u16*   fhw    = (u16*)(p + 4 * R);
  char*  F      = p + 4 * R + 2359296;
  float* gramN  = (float*)F;
  u16*   affT   = (u16*)(F + 4194304);
  u16*   ccat   = (u16*)F;
  u16*   wco    = (u16*)(F + 14155776);

  k_cvt_T<<<dim3(144, 8, 4), 256, 0, stream>>>(x, xbfT, 512, 9216);
  k_cvtw<<<512, 256, 0, stream>>>(w_c, w_o, wco);
  k_conv16<<<dim3(72, 4), 256, 0, stream>>>(w_h, b_h, w_w, b_w, xbfT, fhw);
  k_gemm_conv2<<<dim3(72, 8, 4), 256, 0, stream>>>(wco, xbfT, b_c, b_o, f_ch, f_cha, f_chT);
  k_gram_sk<<<dim3(10, 1, 32), 256, 0, stream>>>(f_ch, part);
  k_softmax512r<<<2048, 256, 0, stream>>>(part, gramN);
  k_cvt_T<<<dim3(8, 8, 4), 256, 0, stream>>>(gramN, affT, 512, 512);
  k_outc<<<dim3(4, 72, 4), 256, 0, stream>>>(f_chT, affT, gamma, outC);
  k_eh<<<384, 256, 0, stream>>>(fhw, ccat);
  k_ew<<<384, 256, 0, stream>>>(fhw, ccat);
  k_softmax192<<<9216, 256, 0, stream>>>(ccat);
  k_tr_plane<<<2048, 256, 0, stream>>>(f_cha, f_chaT);
  k_final_h<<<384, 512, 0, stream>>>(f_chaT, ccat, alpha, outHT);
  k_final_w<<<384, 512, 0, stream>>>(f_cha, ccat, beta, outW);
  k_merge<<<2048, 256, 0, stream>>>(x, outC, outW, outHT, out);
}